// Round 1
// baseline (48.166 us; speedup 1.0000x reference)
//
#include <hip/hip_runtime.h>

#define KCLS 21
#define HW (512 * 512)
#define BATCH 8
#define NBLK 1024
#define BLKSZ 256

// ws layout: uint inter[8*21] | uint aout[8*21] | uint atgt[8*21] | float S[21]

__global__ __launch_bounds__(BLKSZ) void dicece_histo(
    const float* __restrict__ pr, const int* __restrict__ gt,
    unsigned int* __restrict__ ws_inter, unsigned int* __restrict__ ws_aout,
    unsigned int* __restrict__ ws_atgt, float* __restrict__ ws_S)
{
    __shared__ unsigned int s_inter[KCLS], s_aout[KCLS], s_atgt[KCLS];
    __shared__ float s_S[KCLS];
    const int t = threadIdx.x;
    if (t < KCLS) { s_inter[t] = 0u; s_aout[t] = 0u; s_atgt[t] = 0u; s_S[t] = 0.f; }
    __syncthreads();

    const int blocks_per_img = NBLK / BATCH;          // 128
    const int b = blockIdx.x / blocks_per_img;
    const int chunk = blockIdx.x - b * blocks_per_img;
    const int PIXB = HW / blocks_per_img;             // 2048 pixels per block
    const int pix0 = chunk * PIXB;

    const float* __restrict__ pb = pr + (size_t)b * KCLS * HW;  // block-uniform base
    const int*   __restrict__ gb = gt + (size_t)b * HW;

    #pragma unroll
    for (int it = 0; it < PIXB / (BLKSZ * 4); ++it) {   // 2 iterations
        const int pix = pix0 + (it * BLKSZ + t) * 4;

        // 21 coalesced float4 loads, all independent -> deep MLP
        float x[KCLS][4];
        #pragma unroll
        for (int k = 0; k < KCLS; ++k) {
            *reinterpret_cast<float4*>(&x[k][0]) =
                *reinterpret_cast<const float4*>(pb + (size_t)k * HW + pix);
        }
        int g[4];
        *reinterpret_cast<int4*>(&g[0]) = *reinterpret_cast<const int4*>(gb + pix);

        #pragma unroll
        for (int j = 0; j < 4; ++j) {
            // max + argmax (first-occurrence semantics via strict >)
            float m = x[0][j];
            int am = 0;
            #pragma unroll
            for (int k = 1; k < KCLS; ++k) {
                if (x[k][j] > m) { m = x[k][j]; am = k; }
            }
            // sum of exp
            float s = 0.f;
            #pragma unroll
            for (int k = 0; k < KCLS; ++k) s += __expf(x[k][j] - m);
            // select x[gt] without runtime indexing (stays in registers)
            const int gj = g[j];
            float xg = x[0][j];
            #pragma unroll
            for (int k = 1; k < KCLS; ++k) xg = (k == gj) ? x[k][j] : xg;
            const float logp = xg - m - __logf(s);

            atomicAdd(&s_atgt[gj], 1u);
            atomicAdd(&s_aout[am], 1u);
            if (am == gj) atomicAdd(&s_inter[gj], 1u);
            atomicAdd(&s_S[gj], logp);
        }
    }
    __syncthreads();
    if (t < KCLS) {
        atomicAdd(&ws_inter[b * KCLS + t], s_inter[t]);
        atomicAdd(&ws_aout [b * KCLS + t], s_aout[t]);
        atomicAdd(&ws_atgt [b * KCLS + t], s_atgt[t]);
        atomicAdd(&ws_S[t], s_S[t]);
    }
}

__global__ void dicece_final(
    const unsigned int* __restrict__ ws_inter, const unsigned int* __restrict__ ws_aout,
    const unsigned int* __restrict__ ws_atgt, const float* __restrict__ ws_S,
    float* __restrict__ out)
{
    const int k = threadIdx.x;   // one wave; lanes >= 21 contribute 0
    float w = 0.f, Nk = 0.f, Sk = 0.f;
    if (k < KCLS) {
        float dsum = 0.f;
        unsigned int nk = 0u;
        #pragma unroll
        for (int b = 0; b < BATCH; ++b) {
            const float inter = (float)ws_inter[b * KCLS + k];
            const float ao    = (float)ws_aout [b * KCLS + k];
            const float at    = (float)ws_atgt [b * KCLS + k];
            nk += ws_atgt[b * KCLS + k];
            // union + inter == a_out + a_tgt
            dsum += 2.f * inter / (ao + at + 1e-10f);
        }
        w  = 1.f - dsum * 0.125f;   // weight = 1 - dice_class (SAMPLES=8)
        Nk = (float)nk;
        Sk = ws_S[k];
    }
    float num = w * Sk, den = w * Nk, wsum = w;
    #pragma unroll
    for (int off = 32; off > 0; off >>= 1) {
        num  += __shfl_down(num, off);
        den  += __shfl_down(den, off);
        wsum += __shfl_down(wsum, off);
    }
    // BETA * mean(weight) + (-(sum w*logp) / (sum w))
    if (k == 0) out[0] = wsum / (float)KCLS - num / den;
}

extern "C" void kernel_launch(void* const* d_in, const int* in_sizes, int n_in,
                              void* d_out, int out_size, void* d_ws, size_t ws_size,
                              hipStream_t stream) {
    const float* pr = (const float*)d_in[0];
    const int*   gt = (const int*)d_in[1];
    float* out = (float*)d_out;

    unsigned int* ws_inter = (unsigned int*)d_ws;
    unsigned int* ws_aout  = ws_inter + BATCH * KCLS;
    unsigned int* ws_atgt  = ws_aout  + BATCH * KCLS;
    float*        ws_S     = (float*)(ws_atgt + BATCH * KCLS);

    hipMemsetAsync(d_ws, 0, (size_t)(3 * BATCH * KCLS + KCLS) * sizeof(float), stream);
    dicece_histo<<<NBLK, BLKSZ, 0, stream>>>(pr, gt, ws_inter, ws_aout, ws_atgt, ws_S);
    dicece_final<<<1, 64, 0, stream>>>(ws_inter, ws_aout, ws_atgt, ws_S, out);
}